// Round 1
// baseline (187.187 us; speedup 1.0000x reference)
//
#include <hip/hip_runtime.h>
#include <math.h>

// Problem constants
#define NB 16
#define NL 128
#define DIN 512
#define NH 256
#define NTAGS 45
#define NM (NB*NL)          // 2048 rows
#define NJ (NL+1)           // 129 arc columns

// ws layout (floats)
#define H0_OFF    0
#define H1_OFF    (NM*NH)                 // 524288
#define U_OFF     (2*NM*NH)               // 1048576
#define HV_OFF    (3*NM*NH)               // 1572864
#define VROOT_OFF (4*NM*NH)               // 2097152
#define ACC_OFF   (VROOT_OFF + NH)        // 2097408: [0]=loss sum, [1]=done counter

// ---------------------------------------------------------------------------
// Kernel 1: hidden partials, K-split x2.  h_kh = C[:, kh*256:+256] @ W1[same,:]
// grid (64,4,2) = 512 blocks -> 2 blocks/CU (was 1). bias+relu deferred to K2.
// Block (0,0,0) zeroes the loss accumulator + done counter (ws poisoned).
// ---------------------------------------------------------------------------
__global__ __launch_bounds__(256) void gemm_hidden(
    const float* __restrict__ A,   // 2048 x 512
    const float* __restrict__ W,   // 512 x 256
    float* __restrict__ h0,        // 2048 x 256 partial (kh=0)
    float* __restrict__ h1,        // 2048 x 256 partial (kh=1)
    float* __restrict__ accum)
{
    const int K = DIN, N = NH;
    __shared__ float As[16][34];
    __shared__ float Bs[16][68];
    int m0 = blockIdx.x * 32;
    int n0 = blockIdx.y * 64;
    int kbase = blockIdx.z * 256;
    int tid = threadIdx.x;
    if (blockIdx.x == 0 && blockIdx.y == 0 && blockIdx.z == 0 && tid == 0) {
        accum[0] = 0.f;
        ((int*)accum)[1] = 0;
    }
    int tm = tid >> 4, tn = tid & 15;
    int lm = tid >> 2, lk = (tid & 3) * 4;
    int bk = tid >> 4, bn = (tid & 15) * 4;
    float acc[2][4] = {{0.f}};

    for (int k0 = kbase; k0 < kbase + 256; k0 += 16) {
        if (tid < 128) {
            float4 a4 = *(const float4*)&A[(m0 + lm) * K + k0 + lk];
            As[lk + 0][lm] = a4.x; As[lk + 1][lm] = a4.y;
            As[lk + 2][lm] = a4.z; As[lk + 3][lm] = a4.w;
        }
        float4 b4 = *(const float4*)&W[(k0 + bk) * N + n0 + bn];
        *(float4*)&Bs[bk][bn] = b4;
        __syncthreads();
        #pragma unroll
        for (int kk = 0; kk < 16; kk++) {
            float2 a2 = *(const float2*)&As[kk][tm * 2];
            float4 bv = *(const float4*)&Bs[kk][tn * 4];
            float ar[2] = {a2.x, a2.y};
            float br[4] = {bv.x, bv.y, bv.z, bv.w};
            #pragma unroll
            for (int r = 0; r < 2; r++)
                #pragma unroll
                for (int c = 0; c < 4; c++)
                    acc[r][c] += ar[r] * br[c];
        }
        __syncthreads();
    }
    float* out = blockIdx.z ? h1 : h0;
    int col = n0 + tn * 4;
    #pragma unroll
    for (int r = 0; r < 2; r++) {
        int row = m0 + tm * 2 + r;
        *(float4*)&out[row * N + col] =
            make_float4(acc[r][0], acc[r][1], acc[r][2], acc[r][3]);
    }
}

// ---------------------------------------------------------------------------
// Kernel 2: u = hidden@Wa + bp ; hv = hidden@Wb ; vroot = root@Wb
// hidden reconstructed on the fly: relu(h0 + h1 + b1) during A-tile load.
// GEMM M=2048, N=512, K=256; grid (65,8); blockIdx.x==64 = root row.
// ---------------------------------------------------------------------------
__global__ __launch_bounds__(256) void gemm_uv(
    const float* __restrict__ h0,     // 2048 x 256 partial
    const float* __restrict__ h1,     // 2048 x 256 partial
    const float* __restrict__ b1,     // 256 (hidden bias)
    const float* __restrict__ Wp,     // 512 x 256
    const float* __restrict__ bp,     // 256
    const float* __restrict__ root,   // 256
    float* __restrict__ u,            // 2048 x 256
    float* __restrict__ hv,           // 2048 x 256
    float* __restrict__ vroot)        // 256
{
    const int K = NH;
    __shared__ float As[16][34];
    __shared__ float Bs[16][68];
    __shared__ float part[4][64];
    int n0 = blockIdx.y * 64;
    int tid = threadIdx.x;

    if (blockIdx.x == 64) {            // root row block
        if (n0 < NH) return;
        int col = (n0 - NH) + (tid & 63);
        int kc = tid >> 6;
        float p = 0.f;
        #pragma unroll 8
        for (int c = kc * 64; c < kc * 64 + 64; c++)
            p += root[c] * Wp[(NH + c) * NH + col];
        part[kc][tid & 63] = p;
        __syncthreads();
        if (tid < 64)
            vroot[(n0 - NH) + tid] = part[0][tid] + part[1][tid]
                                   + part[2][tid] + part[3][tid];
        return;
    }

    int m0 = blockIdx.x * 32;
    bool isU = (n0 < NH);
    int tm = tid >> 4, tn = tid & 15;
    int lm = tid >> 2, lk = (tid & 3) * 4;
    int bk = tid >> 4, bn = (tid & 15) * 4;
    float acc[2][4] = {{0.f}};

    for (int k0 = 0; k0 < K; k0 += 16) {
        if (tid < 128) {
            size_t base = (size_t)(m0 + lm) * NH + k0 + lk;
            float4 a0 = *(const float4*)&h0[base];
            float4 a1 = *(const float4*)&h1[base];
            float4 bv = *(const float4*)&b1[k0 + lk];
            As[lk + 0][lm] = fmaxf(a0.x + a1.x + bv.x, 0.f);
            As[lk + 1][lm] = fmaxf(a0.y + a1.y + bv.y, 0.f);
            As[lk + 2][lm] = fmaxf(a0.z + a1.z + bv.z, 0.f);
            As[lk + 3][lm] = fmaxf(a0.w + a1.w + bv.w, 0.f);
        }
        int c = k0 + bk;
        float4 b4;
        if (isU) b4 = *(const float4*)&Wp[c * NH + n0 + bn];
        else     b4 = *(const float4*)&Wp[(NH + c) * NH + (n0 - NH) + bn];
        *(float4*)&Bs[bk][bn] = b4;
        __syncthreads();
        #pragma unroll
        for (int kk = 0; kk < 16; kk++) {
            float2 a2 = *(const float2*)&As[kk][tm * 2];
            float4 bv = *(const float4*)&Bs[kk][tn * 4];
            float ar[2] = {a2.x, a2.y};
            float br[4] = {bv.x, bv.y, bv.z, bv.w};
            #pragma unroll
            for (int r = 0; r < 2; r++)
                #pragma unroll
                for (int cc = 0; cc < 4; cc++)
                    acc[r][cc] += ar[r] * br[cc];
        }
        __syncthreads();
    }
    if (isU) {
        int col = n0 + tn * 4;
        float4 bb = *(const float4*)&bp[col];
        #pragma unroll
        for (int r = 0; r < 2; r++) {
            int row = m0 + tm * 2 + r;
            *(float4*)&u[row * NH + col] = make_float4(
                acc[r][0] + bb.x, acc[r][1] + bb.y,
                acc[r][2] + bb.z, acc[r][3] + bb.w);
        }
    } else {
        int col = (n0 - NH) + tn * 4;
        #pragma unroll
        for (int r = 0; r < 2; r++) {
            int row = m0 + tm * 2 + r;
            *(float4*)&hv[row * NH + col] = make_float4(
                acc[r][0], acc[r][1], acc[r][2], acc[r][3]);
        }
    }
}

// ---------------------------------------------------------------------------
// Kernel 3 (fused K3+K4+finalize): per block = (batch b, 8-row tile).
// Stages v = [vroot; hv[b]] (129 x 64 per k-chunk) + u-tile + W_arc + W_lab^T
// in LDS; accumulates full 129-wide arc-score rows in registers
// (thread = (row i = tid>>5, jq = tid&31); j = jq + 32q, q<4; j=128 via a
// cooperative per-lane 2-kk partial reduced at the end). Arc softmax CE via
// half-wave shuffles. Label head reuses the resident v tile (sel column =
// v_s[arc]). One atomicAdd per block; last block (done counter) finalizes.
// Blocks with i0 >= slen skip everything except the counter.
// LDS strides chosen for <=2-way bank aliasing (free): VS=66, WLS=66; US=68
// (16B-aligned rows for float4 staging; u reads are broadcast anyway).
// ---------------------------------------------------------------------------
#define VS 66
#define US 68
#define WLS 66
#define NBLK 256

__global__ __launch_bounds__(256) void score_loss_kernel(
    const float* __restrict__ u, const float* __restrict__ hv,
    const float* __restrict__ vroot, const float* __restrict__ W_arc,
    const float* __restrict__ W_lab, const float* __restrict__ b_lab,
    const int* __restrict__ slens, const int* __restrict__ arcs,
    const int* __restrict__ labels,
    float* __restrict__ accum, float* __restrict__ out)
{
    __shared__ float v_s[NJ * VS];        // 8514 f
    __shared__ float u_s[8 * US];         // 544 f
    __shared__ float sel_s[8 * US];       // 544 f
    __shared__ float wl_s[NTAGS * WLS];   // 2970 f (W_lab chunk, transposed)
    __shared__ float wa_s[NH];
    __shared__ float ll_s[8 * 46];
    __shared__ float ce_s[8];
    __shared__ int   arc_s[8], lab_s[8];

    int bb = blockIdx.x;
    int i0 = blockIdx.y * 8;
    int tid = threadIdx.x;
    int slen = slens[bb];

    if (i0 < slen) {
        wa_s[tid] = W_arc[tid];
        if (tid < 8) {
            int rg = bb * NL + i0 + tid;
            arc_s[tid] = arcs[rg];
            lab_s[tid] = labels[rg];
        }
        int i_loc = tid >> 5;          // 0..7: row within tile
        int jq = tid & 31;             // j-lane
        // label cell mapping: 360 cells = 8 rows x 45 tags
        int c0 = tid;        int ti0 = c0 / 45, tg0 = c0 - 45 * ti0;
        int c1 = tid + 256;  int ti1 = c1 / 45, tg1 = c1 - 45 * ti1;
        bool has1 = (c1 < 8 * NTAGS);
        float lg0 = b_lab[tg0];
        float lg1 = has1 ? b_lab[tg1] : 0.f;
        float acc0 = 0.f, acc1 = 0.f, acc2 = 0.f, acc3 = 0.f, s128 = 0.f;

        for (int c = 0; c < 4; ++c) {
            int k0 = c * 64;
            // ---- stage u tile: 8 x 64 = 128 float4 ----
            if (tid < 128) {
                int ui = tid >> 4, kq = (tid & 15) * 4;
                float4 a4 = *(const float4*)
                    &u[(size_t)(bb * NL + i0 + ui) * NH + k0 + kq];
                *(float4*)&u_s[ui * US + kq] = a4;
            }
            // ---- stage v tile: 129 x 64 (float2 stores: rows 8B-aligned) ----
            for (int idx = tid; idx < NJ * 16; idx += 256) {
                int j = idx >> 4, kq = (idx & 15) * 4;
                const float* src = (j == 0) ? (vroot + k0 + kq)
                    : (hv + (size_t)(bb * NL + j - 1) * NH + k0 + kq);
                float4 v4 = *(const float4*)src;
                float* dst = &v_s[j * VS + kq];
                *(float2*)dst       = make_float2(v4.x, v4.y);
                *(float2*)(dst + 2) = make_float2(v4.z, v4.w);
            }
            // ---- stage W_lab chunk transposed: wl_s[tag][k_rel] ----
            for (int e = tid; e < 64 * NTAGS; e += 256) {
                float val = W_lab[(size_t)k0 * NTAGS + e];
                int kr = e / NTAGS, tg = e - NTAGS * kr;
                wl_s[tg * WLS + kr] = val;
            }
            __syncthreads();

            // ---- arc scores (j = jq+32q, q<4) ----
            const float* ur = &u_s[i_loc * US];
            #pragma unroll
            for (int kk2 = 0; kk2 < 32; ++kk2) {
                int kk = kk2 * 2;
                float2 uv = *(const float2*)&ur[kk];
                float2 wv = *(const float2*)&wa_s[k0 + kk];
                float2 va = *(const float2*)&v_s[jq * VS + kk];
                float2 vb = *(const float2*)&v_s[(jq + 32) * VS + kk];
                float2 vc = *(const float2*)&v_s[(jq + 64) * VS + kk];
                float2 vd = *(const float2*)&v_s[(jq + 96) * VS + kk];
                acc0 += fmaxf(uv.x + va.x, 0.f) * wv.x + fmaxf(uv.y + va.y, 0.f) * wv.y;
                acc1 += fmaxf(uv.x + vb.x, 0.f) * wv.x + fmaxf(uv.y + vb.y, 0.f) * wv.y;
                acc2 += fmaxf(uv.x + vc.x, 0.f) * wv.x + fmaxf(uv.y + vc.y, 0.f) * wv.y;
                acc3 += fmaxf(uv.x + vd.x, 0.f) * wv.x + fmaxf(uv.y + vd.y, 0.f) * wv.y;
            }
            // ---- j=128 column: each lane takes 2 kk, reduced after loop ----
            {
                int kk = jq * 2;
                float2 uv = *(const float2*)&ur[kk];
                float2 wv = *(const float2*)&wa_s[k0 + kk];
                float2 vv = *(const float2*)&v_s[128 * VS + kk];
                s128 += fmaxf(uv.x + vv.x, 0.f) * wv.x
                      + fmaxf(uv.y + vv.y, 0.f) * wv.y;
            }
            // ---- sel staging: sel_s[i][kk] = relu(u + v[arc_i]) ----
            {
                int a = arc_s[i_loc];
                int kk = jq * 2;
                float2 uv = *(const float2*)&ur[kk];
                float2 vv = *(const float2*)&v_s[a * VS + kk];
                *(float2*)&sel_s[i_loc * US + kk] = make_float2(
                    fmaxf(uv.x + vv.x, 0.f), fmaxf(uv.y + vv.y, 0.f));
            }
            __syncthreads();

            // ---- label logits: cell = (row ti, tag tg), k-chunk dot ----
            {
                const float* sp = &sel_s[ti0 * US];
                const float* wp = &wl_s[tg0 * WLS];
                float s = 0.f;
                #pragma unroll
                for (int kk2 = 0; kk2 < 32; ++kk2) {
                    float2 sv = *(const float2*)&sp[kk2 * 2];
                    float2 wv = *(const float2*)&wp[kk2 * 2];
                    s += sv.x * wv.x + sv.y * wv.y;
                }
                lg0 += s;
            }
            if (has1) {
                const float* sp = &sel_s[ti1 * US];
                const float* wp = &wl_s[tg1 * WLS];
                float s = 0.f;
                #pragma unroll
                for (int kk2 = 0; kk2 < 32; ++kk2) {
                    float2 sv = *(const float2*)&sp[kk2 * 2];
                    float2 wv = *(const float2*)&wp[kk2 * 2];
                    s += sv.x * wv.x + sv.y * wv.y;
                }
                lg1 += s;
            }
            __syncthreads();
        }

        // ---- publish label logits ----
        ll_s[ti0 * 46 + tg0] = lg0;
        if (has1) ll_s[ti1 * 46 + tg1] = lg1;

        // ---- arc softmax CE (half-wave = one row) ----
        float m = fmaxf(fmaxf(acc0, acc1), fmaxf(acc2, acc3));
        #pragma unroll
        for (int off = 16; off > 0; off >>= 1)
            m = fmaxf(m, __shfl_xor(m, off));
        float s1 = s128;
        #pragma unroll
        for (int off = 16; off > 0; off >>= 1)
            s1 += __shfl_xor(s1, off);
        m = fmaxf(m, s1);
        float e = expf(acc0 - m) + expf(acc1 - m)
                + expf(acc2 - m) + expf(acc3 - m);
        #pragma unroll
        for (int off = 16; off > 0; off >>= 1)
            e += __shfl_xor(e, off);
        e += expf(s1 - m);
        int a = arc_s[i_loc];
        float cand = (a < 32) ? acc0 : (a < 64) ? acc1 : (a < 96) ? acc2 : acc3;
        float s_a = __shfl(cand, (tid & 32) + (a & 31), 64);
        if (a == 128) s_a = s1;
        float arc_ce = (m + logf(e)) - s_a;
        __syncthreads();   // ll_s ready

        // ---- label softmax CE ----
        float y0 = (jq < NTAGS)      ? ll_s[i_loc * 46 + jq]      : -INFINITY;
        float y1 = (jq + 32 < NTAGS) ? ll_s[i_loc * 46 + jq + 32] : -INFINITY;
        float m2 = fmaxf(y0, y1);
        #pragma unroll
        for (int off = 16; off > 0; off >>= 1)
            m2 = fmaxf(m2, __shfl_xor(m2, off));
        float e2 = ((jq < NTAGS) ? expf(y0 - m2) : 0.f)
                 + ((jq + 32 < NTAGS) ? expf(y1 - m2) : 0.f);
        #pragma unroll
        for (int off = 16; off > 0; off >>= 1)
            e2 += __shfl_xor(e2, off);
        float lab_ce = (m2 + logf(e2)) - ll_s[i_loc * 46 + lab_s[i_loc]];

        float tot = ((i0 + i_loc) < slen) ? (arc_ce + lab_ce) : 0.f;
        if (jq == 0) ce_s[i_loc] = tot;
        __syncthreads();
        if (tid == 0) {
            float bs = ce_s[0] + ce_s[1] + ce_s[2] + ce_s[3]
                     + ce_s[4] + ce_s[5] + ce_s[6] + ce_s[7];
            atomicAdd(accum, bs);
        }
    }

    // ---- done counter; last block finalizes ----
    if (tid == 0) {
        __threadfence();
        int prev = atomicAdd((int*)accum + 1, 1);
        if (prev == NBLK - 1) {
            int d = 0;
            #pragma unroll
            for (int q = 0; q < NB; ++q) d += slens[q];
            float s = atomicAdd(accum, 0.f);   // coherent read
            out[0] = 0.5f * s / fmaxf((float)d, 1.f);
        }
    }
}

extern "C" void kernel_launch(void* const* d_in, const int* in_sizes, int n_in,
                              void* d_out, int out_size, void* d_ws, size_t ws_size,
                              hipStream_t stream) {
    (void)in_sizes; (void)n_in; (void)out_size; (void)ws_size;
    const float* ctx   = (const float*)d_in[0];
    const int*   slens = (const int*)  d_in[1];
    const int*   arcs  = (const int*)  d_in[2];
    const int*   labs  = (const int*)  d_in[3];
    const float* W1    = (const float*)d_in[4];
    const float* b1    = (const float*)d_in[5];
    const float* root  = (const float*)d_in[6];
    const float* Wp    = (const float*)d_in[7];
    const float* bp    = (const float*)d_in[8];
    const float* W_arc = (const float*)d_in[9];
    // d_in[10] = b_arc: constant shift, cancels in arc log-softmax CE
    const float* W_lab = (const float*)d_in[11];
    const float* b_lab = (const float*)d_in[12];
    float* out = (float*)d_out;

    float* ws    = (float*)d_ws;
    float* h0    = ws + H0_OFF;
    float* h1    = ws + H1_OFF;
    float* u     = ws + U_OFF;
    float* hv    = ws + HV_OFF;
    float* vroot = ws + VROOT_OFF;
    float* accum = ws + ACC_OFF;

    gemm_hidden<<<dim3(NM / 32, NH / 64, 2), 256, 0, stream>>>(ctx, W1, h0, h1, accum);
    gemm_uv<<<dim3(65, 8), 256, 0, stream>>>(h0, h1, b1, Wp, bp, root, u, hv, vroot);
    score_loss_kernel<<<dim3(NB, 16), 256, 0, stream>>>(u, hv, vroot, W_arc,
                                                        W_lab, b_lab, slens,
                                                        arcs, labs, accum, out);
}

// Round 2
// 166.204 us; speedup vs baseline: 1.1262x; 1.1262x over previous
//
#include <hip/hip_runtime.h>
#include <math.h>

// Problem constants
#define NB 16
#define NL 128
#define DIN 512
#define NH 256
#define NTAGS 45
#define NM (NB*NL)          // 2048 rows
#define NJ (NL+1)           // 129 arc columns

// ws layout (floats)
#define H0_OFF    0
#define H1_OFF    (NM*NH)                 // 524288
#define U_OFF     (2*NM*NH)               // 1048576
#define HV_OFF    (3*NM*NH)               // 1572864
#define VROOT_OFF (4*NM*NH)               // 2097152
#define ACC_OFF   (VROOT_OFF + NH)        // 2097408: [0]=loss sum, [1]=done counter

// ---------------------------------------------------------------------------
// Kernel 1: hidden partials, K-split x2.  h_kh = C[:, kh*256:+256] @ W1[same,:]
// grid (64,4,2) = 512 blocks -> 2 blocks/CU. bias+relu deferred to K2.
// Block (0,0,0) zeroes the loss accumulator + done counter (ws poisoned).
// ---------------------------------------------------------------------------
__global__ __launch_bounds__(256) void gemm_hidden(
    const float* __restrict__ A,   // 2048 x 512
    const float* __restrict__ W,   // 512 x 256
    float* __restrict__ h0,        // 2048 x 256 partial (kh=0)
    float* __restrict__ h1,        // 2048 x 256 partial (kh=1)
    float* __restrict__ accum)
{
    const int K = DIN, N = NH;
    __shared__ float As[16][34];
    __shared__ float Bs[16][68];
    int m0 = blockIdx.x * 32;
    int n0 = blockIdx.y * 64;
    int kbase = blockIdx.z * 256;
    int tid = threadIdx.x;
    if (blockIdx.x == 0 && blockIdx.y == 0 && blockIdx.z == 0 && tid == 0) {
        accum[0] = 0.f;
        ((int*)accum)[1] = 0;
    }
    int tm = tid >> 4, tn = tid & 15;
    int lm = tid >> 2, lk = (tid & 3) * 4;
    int bk = tid >> 4, bn = (tid & 15) * 4;
    float acc[2][4] = {{0.f}};

    for (int k0 = kbase; k0 < kbase + 256; k0 += 16) {
        if (tid < 128) {
            float4 a4 = *(const float4*)&A[(m0 + lm) * K + k0 + lk];
            As[lk + 0][lm] = a4.x; As[lk + 1][lm] = a4.y;
            As[lk + 2][lm] = a4.z; As[lk + 3][lm] = a4.w;
        }
        float4 b4 = *(const float4*)&W[(k0 + bk) * N + n0 + bn];
        *(float4*)&Bs[bk][bn] = b4;
        __syncthreads();
        #pragma unroll
        for (int kk = 0; kk < 16; kk++) {
            float2 a2 = *(const float2*)&As[kk][tm * 2];
            float4 bv = *(const float4*)&Bs[kk][tn * 4];
            float ar[2] = {a2.x, a2.y};
            float br[4] = {bv.x, bv.y, bv.z, bv.w};
            #pragma unroll
            for (int r = 0; r < 2; r++)
                #pragma unroll
                for (int c = 0; c < 4; c++)
                    acc[r][c] += ar[r] * br[c];
        }
        __syncthreads();
    }
    float* out = blockIdx.z ? h1 : h0;
    int col = n0 + tn * 4;
    #pragma unroll
    for (int r = 0; r < 2; r++) {
        int row = m0 + tm * 2 + r;
        *(float4*)&out[row * N + col] =
            make_float4(acc[r][0], acc[r][1], acc[r][2], acc[r][3]);
    }
}

// ---------------------------------------------------------------------------
// Kernel 2: u = hidden@Wa + bp ; hv = hidden@Wb ; vroot = root@Wb
// hidden reconstructed on the fly: relu(h0 + h1 + b1) during A-tile load.
// GEMM M=2048, N=512, K=256; grid (65,8); blockIdx.x==64 = root row.
// ---------------------------------------------------------------------------
__global__ __launch_bounds__(256) void gemm_uv(
    const float* __restrict__ h0,     // 2048 x 256 partial
    const float* __restrict__ h1,     // 2048 x 256 partial
    const float* __restrict__ b1,     // 256 (hidden bias)
    const float* __restrict__ Wp,     // 512 x 256
    const float* __restrict__ bp,     // 256
    const float* __restrict__ root,   // 256
    float* __restrict__ u,            // 2048 x 256
    float* __restrict__ hv,           // 2048 x 256
    float* __restrict__ vroot)        // 256
{
    const int K = NH;
    __shared__ float As[16][34];
    __shared__ float Bs[16][68];
    __shared__ float part[4][64];
    int n0 = blockIdx.y * 64;
    int tid = threadIdx.x;

    if (blockIdx.x == 64) {            // root row block
        if (n0 < NH) return;
        int col = (n0 - NH) + (tid & 63);
        int kc = tid >> 6;
        float p = 0.f;
        #pragma unroll 8
        for (int c = kc * 64; c < kc * 64 + 64; c++)
            p += root[c] * Wp[(NH + c) * NH + col];
        part[kc][tid & 63] = p;
        __syncthreads();
        if (tid < 64)
            vroot[(n0 - NH) + tid] = part[0][tid] + part[1][tid]
                                   + part[2][tid] + part[3][tid];
        return;
    }

    int m0 = blockIdx.x * 32;
    bool isU = (n0 < NH);
    int tm = tid >> 4, tn = tid & 15;
    int lm = tid >> 2, lk = (tid & 3) * 4;
    int bk = tid >> 4, bn = (tid & 15) * 4;
    float acc[2][4] = {{0.f}};

    for (int k0 = 0; k0 < K; k0 += 16) {
        if (tid < 128) {
            size_t base = (size_t)(m0 + lm) * NH + k0 + lk;
            float4 a0 = *(const float4*)&h0[base];
            float4 a1 = *(const float4*)&h1[base];
            float4 bv = *(const float4*)&b1[k0 + lk];
            As[lk + 0][lm] = fmaxf(a0.x + a1.x + bv.x, 0.f);
            As[lk + 1][lm] = fmaxf(a0.y + a1.y + bv.y, 0.f);
            As[lk + 2][lm] = fmaxf(a0.z + a1.z + bv.z, 0.f);
            As[lk + 3][lm] = fmaxf(a0.w + a1.w + bv.w, 0.f);
        }
        int c = k0 + bk;
        float4 b4;
        if (isU) b4 = *(const float4*)&Wp[c * NH + n0 + bn];
        else     b4 = *(const float4*)&Wp[(NH + c) * NH + (n0 - NH) + bn];
        *(float4*)&Bs[bk][bn] = b4;
        __syncthreads();
        #pragma unroll
        for (int kk = 0; kk < 16; kk++) {
            float2 a2 = *(const float2*)&As[kk][tm * 2];
            float4 bv = *(const float4*)&Bs[kk][tn * 4];
            float ar[2] = {a2.x, a2.y};
            float br[4] = {bv.x, bv.y, bv.z, bv.w};
            #pragma unroll
            for (int r = 0; r < 2; r++)
                #pragma unroll
                for (int cc = 0; cc < 4; cc++)
                    acc[r][cc] += ar[r] * br[cc];
        }
        __syncthreads();
    }
    if (isU) {
        int col = n0 + tn * 4;
        float4 bb = *(const float4*)&bp[col];
        #pragma unroll
        for (int r = 0; r < 2; r++) {
            int row = m0 + tm * 2 + r;
            *(float4*)&u[row * NH + col] = make_float4(
                acc[r][0] + bb.x, acc[r][1] + bb.y,
                acc[r][2] + bb.z, acc[r][3] + bb.w);
        }
    } else {
        int col = (n0 - NH) + tn * 4;
        #pragma unroll
        for (int r = 0; r < 2; r++) {
            int row = m0 + tm * 2 + r;
            *(float4*)&hv[row * NH + col] = make_float4(
                acc[r][0], acc[r][1], acc[r][2], acc[r][3]);
        }
    }
}

// ---------------------------------------------------------------------------
// Kernel 3 (fused scores+loss+finalize), wave-per-row layout.
// Block = 4 waves = 4 rows (b, i0..i0+3); grid (NB, 32) = 512 blocks (2/CU).
// Per k-chunk (64 k): stage v k-major as float2 v2[kk2][j] (conflict-free
// per-lane j reads), W_lab chunk transposed. Each wave computes its row's
// full 129-wide scores in registers: lane owns j=lane and j=lane+64;
// j=128 + sel (label input) handled by lanes 0..31 on per-lane k-slices.
// Arc softmax + label softmax entirely via 64-lane shuffles. One atomicAdd
// per block; done-counter finalize (no extra launch).
// ---------------------------------------------------------------------------
#define NBLK (NB*32)   // 512

__global__ __launch_bounds__(256) void score_loss_kernel(
    const float* __restrict__ u, const float* __restrict__ hv,
    const float* __restrict__ vroot, const float* __restrict__ W_arc,
    const float* __restrict__ W_lab, const float* __restrict__ b_lab,
    const int* __restrict__ slens, const int* __restrict__ arcs,
    const int* __restrict__ labels,
    float* __restrict__ accum, float* __restrict__ out)
{
    __shared__ float2 v2_s[32][129];   // [kk2][j]  33,024 B
    __shared__ float2 u2_s[4][128];    // [row][kk2] 4,096 B
    __shared__ float2 wa2_s[128];      //            1,024 B
    __shared__ float2 wl2_s[32][46];   // [kk2][tag] 11,776 B
    __shared__ float2 sel2_s[32][5];   // [kk2][row] 1,280 B
    __shared__ float  ce_s[4];
    __shared__ int    arc_s[4], lab_s[4];

    int bb = blockIdx.x;
    int i0 = blockIdx.y * 4;
    int tid = threadIdx.x;
    int w = tid >> 6;          // wave index = local row
    int lane = tid & 63;
    int slen = slens[bb];

    if (i0 < slen) {
        // ---- one-time staging: u rows (4 x 256), W_arc, arcs/labels ----
        {
            int r = tid >> 6, kq = (tid & 63) * 4;
            float4 a4 = *(const float4*)&u[(size_t)(bb * NL + i0 + r) * NH + kq];
            u2_s[r][(kq >> 1) + 0] = make_float2(a4.x, a4.y);
            u2_s[r][(kq >> 1) + 1] = make_float2(a4.z, a4.w);
        }
        if (tid < 128)
            wa2_s[tid] = *(const float2*)&W_arc[tid * 2];
        if (tid < 4) {
            int rg = bb * NL + i0 + tid;
            arc_s[tid] = arcs[rg];
            lab_s[tid] = labels[rg];
        }

        float acc1 = 0.f, acc2 = 0.f, s128 = 0.f, lacc = 0.f;

        for (int c = 0; c < 4; ++c) {
            int k0 = c * 64;
            // ---- stage v chunk k-major: 129 j x 64 k ----
            for (int idx = tid; idx < NJ * 16; idx += 256) {
                int j = idx >> 4, kq = (idx & 15) * 4;
                const float* src = (j == 0) ? (vroot + k0 + kq)
                    : (hv + (size_t)(bb * NL + j - 1) * NH + k0 + kq);
                float4 v4 = *(const float4*)src;
                v2_s[(kq >> 1) + 0][j] = make_float2(v4.x, v4.y);
                v2_s[(kq >> 1) + 1][j] = make_float2(v4.z, v4.w);
            }
            // ---- stage W_lab chunk transposed: wl2[kk2][t] ----
            for (int e = tid; e < 64 * NTAGS; e += 256) {
                int kk = e / NTAGS, t = e - NTAGS * kk;
                ((float*)&wl2_s[kk >> 1][t])[kk & 1] =
                    W_lab[(size_t)(k0 + kk) * NTAGS + t];
            }
            __syncthreads();

            // ---- arc scores: lane covers j=lane and j=lane+64 ----
            const float2* urow = u2_s[w] + (k0 >> 1);
            const float2* warow = wa2_s + (k0 >> 1);
            #pragma unroll 8
            for (int kk2 = 0; kk2 < 32; ++kk2) {
                float2 u2 = urow[kk2];
                float2 w2 = warow[kk2];
                float2 va = v2_s[kk2][lane];
                float2 vb = v2_s[kk2][lane + 64];
                acc1 += fmaxf(u2.x + va.x, 0.f) * w2.x
                      + fmaxf(u2.y + va.y, 0.f) * w2.y;
                acc2 += fmaxf(u2.x + vb.x, 0.f) * w2.x
                      + fmaxf(u2.y + vb.y, 0.f) * w2.y;
            }
            // ---- j=128 partial + sel staging (lanes 0..31, kk2=lane) ----
            if (lane < 32) {
                float2 u2 = urow[lane];
                float2 w2 = warow[lane];
                float2 vv = v2_s[lane][128];
                s128 += fmaxf(u2.x + vv.x, 0.f) * w2.x
                      + fmaxf(u2.y + vv.y, 0.f) * w2.y;
                float2 vs = v2_s[lane][arc_s[w]];
                sel2_s[lane][w] = make_float2(fmaxf(u2.x + vs.x, 0.f),
                                              fmaxf(u2.y + vs.y, 0.f));
            }
            // ---- label logit partials: lane = tag ----
            if (lane < NTAGS) {
                #pragma unroll 8
                for (int kk2 = 0; kk2 < 32; ++kk2) {
                    float2 s2 = sel2_s[kk2][w];
                    float2 wv = wl2_s[kk2][lane];
                    lacc += s2.x * wv.x + s2.y * wv.y;
                }
            }
            __syncthreads();
        }

        // ---- arc softmax CE (full-wave shuffles) ----
        float s128t = s128;
        #pragma unroll
        for (int off = 32; off > 0; off >>= 1)
            s128t += __shfl_xor(s128t, off);
        float m = fmaxf(acc1, acc2);
        #pragma unroll
        for (int off = 32; off > 0; off >>= 1)
            m = fmaxf(m, __shfl_xor(m, off));
        m = fmaxf(m, s128t);
        float e = expf(acc1 - m) + expf(acc2 - m);
        #pragma unroll
        for (int off = 32; off > 0; off >>= 1)
            e += __shfl_xor(e, off);
        e += expf(s128t - m);
        int a = arc_s[w];
        float cand = (a < 64) ? acc1 : acc2;
        float s_a = __shfl(cand, a & 63, 64);
        if (a == 128) s_a = s128t;
        float arc_ce = (m + logf(e)) - s_a;

        // ---- label softmax CE ----
        float logit = (lane < NTAGS) ? (lacc + b_lab[lane]) : -INFINITY;
        float m2 = logit;
        #pragma unroll
        for (int off = 32; off > 0; off >>= 1)
            m2 = fmaxf(m2, __shfl_xor(m2, off));
        float e2 = (lane < NTAGS) ? expf(logit - m2) : 0.f;
        #pragma unroll
        for (int off = 32; off > 0; off >>= 1)
            e2 += __shfl_xor(e2, off);
        float l_t = __shfl(logit, lab_s[w], 64);
        float lab_ce = (m2 + logf(e2)) - l_t;

        float tot = ((i0 + w) < slen) ? (arc_ce + lab_ce) : 0.f;
        if (lane == 0) ce_s[w] = tot;
        __syncthreads();
        if (tid == 0)
            atomicAdd(accum, ce_s[0] + ce_s[1] + ce_s[2] + ce_s[3]);
    }

    // ---- done counter; last block finalizes ----
    if (tid == 0) {
        __threadfence();
        int prev = atomicAdd((int*)accum + 1, 1);
        if (prev == NBLK - 1) {
            int d = 0;
            #pragma unroll
            for (int q = 0; q < NB; ++q) d += slens[q];
            float s = atomicAdd(accum, 0.f);   // coherent read
            out[0] = 0.5f * s / fmaxf((float)d, 1.f);
        }
    }
}

extern "C" void kernel_launch(void* const* d_in, const int* in_sizes, int n_in,
                              void* d_out, int out_size, void* d_ws, size_t ws_size,
                              hipStream_t stream) {
    (void)in_sizes; (void)n_in; (void)out_size; (void)ws_size;
    const float* ctx   = (const float*)d_in[0];
    const int*   slens = (const int*)  d_in[1];
    const int*   arcs  = (const int*)  d_in[2];
    const int*   labs  = (const int*)  d_in[3];
    const float* W1    = (const float*)d_in[4];
    const float* b1    = (const float*)d_in[5];
    const float* root  = (const float*)d_in[6];
    const float* Wp    = (const float*)d_in[7];
    const float* bp    = (const float*)d_in[8];
    const float* W_arc = (const float*)d_in[9];
    // d_in[10] = b_arc: constant shift, cancels in arc log-softmax CE
    const float* W_lab = (const float*)d_in[11];
    const float* b_lab = (const float*)d_in[12];
    float* out = (float*)d_out;

    float* ws    = (float*)d_ws;
    float* h0    = ws + H0_OFF;
    float* h1    = ws + H1_OFF;
    float* u     = ws + U_OFF;
    float* hv    = ws + HV_OFF;
    float* vroot = ws + VROOT_OFF;
    float* accum = ws + ACC_OFF;

    gemm_hidden<<<dim3(NM / 32, NH / 64, 2), 256, 0, stream>>>(ctx, W1, h0, h1, accum);
    gemm_uv<<<dim3(65, 8), 256, 0, stream>>>(h0, h1, b1, Wp, bp, root, u, hv, vroot);
    score_loss_kernel<<<dim3(NB, 32), 256, 0, stream>>>(u, hv, vroot, W_arc,
                                                        W_lab, b_lab, slens,
                                                        arcs, labs, accum, out);
}